// Round 8
// baseline (184.921 us; speedup 1.0000x reference)
//
#include <hip/hip_runtime.h>
#include <stdint.h>

// Fastfood 2D conv, MI355X. fp32 I/O:
// input (16,256,32,32), B/G/S (1,4096), bias (512), P (4096) i32 -> out (16,512,32,32).
// Per pixel: patch j=kk*256+ch (2304, pad 4096), *B, FWHT4096, perm P, *G, FWHT4096,
// *S[0:512]+bias.  j decomposes as (jA,jB,jC) 16x16x16; FWHT4096 = H16 x H16 x H16
// (separable, order-free; Sylvester H[r][k] = (-1)^popc(r&k)).
//
// R10: MFMA reformulation. Each WAVE owns pixel quads p=w and p=w+4 end-to-end.
//  Per pixel, tiles X_a[jB][jC] (a=jA). Both tile axes via two chained
//  v_mfma_f32_16x16x16_f16: D1 = X*H (A=X,B=H), D2 = H*D1 (A=H, B=D1 fed
//  DIRECTLY: D-layout row=4q+i [verified m89] matches B's k grouping; all
//  operand fragments stored with the same (q,i)->4q+i convention, so any hw
//  k-permutation cancels in the contraction). a-axis: pass0 = register FWHT16
//  across tiles; pass1 truncation (oc<512 needs only H-rows 0,1 of the a-round)
//  = MFMA C-accumulation: s += H*D1' (sum), d += (+-H)*D1' (alt-sum).
//  LDS per quad: ONLY the perm stage+gather (4px uint2 packs, sigma-swizzled
//  slots), serialized across waves in 4 barrier slots (buf2 32KB shared).
//  Barriers/block: ~11 (was ~34). Butterfly VALU -> idle MFMA pipe.
// R9 epilogue kept: h2 packs staged to buf2, cooperative float4 stores.
// LDS: s_in 48KB + buf2 32KB = 80KB -> 2 blocks/CU.

typedef _Float16 h4 __attribute__((ext_vector_type(4)));
typedef float f4 __attribute__((ext_vector_type(4)));

__device__ __forceinline__ uint16_t f2h16(float f) {
    union { _Float16 h; uint16_t u; } c; c.h = (_Float16)f; return c.u;
}
__device__ __forceinline__ float h16f(uint16_t u) {
    union { _Float16 h; uint16_t u; } c; c.u = u; return (float)c.h;
}
__device__ __forceinline__ uint32_t pkh2(float a, float b) {
    return (uint32_t)f2h16(a) | ((uint32_t)f2h16(b) << 16);
}
__device__ __forceinline__ uint32_t lolo(uint32_t a, uint32_t b) {
    return (a & 0xffffu) | (b << 16);
}
__device__ __forceinline__ uint32_t hihi(uint32_t a, uint32_t b) {
    return (a >> 16) | (b & 0xffff0000u);
}
__device__ __forceinline__ h4 u2h4(uint32_t lo, uint32_t hi) {
    union { h4 h; uint2 u; } c; c.u = make_uint2(lo, hi); return c.h;
}
__device__ __forceinline__ uint2 h4u(h4 v) {
    union { h4 h; uint2 u; } c; c.h = v; return c.u;
}
__device__ __forceinline__ h4 cvt4(f4 v) {
    h4 r; r[0] = (_Float16)v[0]; r[1] = (_Float16)v[1];
    r[2] = (_Float16)v[2]; r[3] = (_Float16)v[3]; return r;
}
__device__ __forceinline__ f4 mfma16(h4 a, h4 b, f4 c) {
    return __builtin_amdgcn_mfma_f32_16x16x16f16(a, b, c, 0, 0, 0);
}
// sigma: value j lives at buf2 slot sigma(j). Chosen so the OWNING lane's 4
// i-values (j bits 4-5) are slot-contiguous (b128 stage writes), with a lane
// XOR for bank spread. Gather recomputes sigma(P[j']).
__device__ __forceinline__ int sigma_slot(int j) {
    const int L = (((j >> 6) & 3) << 4) | (j & 15);   // owning lane 16q+c0
    return ((j >> 8) << 8) + ((L ^ ((L >> 2) & 3)) << 2) + ((j >> 4) & 3);
}

__global__ __launch_bounds__(256, 2)
void fastfood_kernel(const float* __restrict__ in,
                     const float* __restrict__ Bm,
                     const float* __restrict__ Gm,
                     const float* __restrict__ Sm,
                     const float* __restrict__ bias,
                     const int* __restrict__ P,
                     float* __restrict__ out)
{
    // s_in: [kh(3)][iwm(8)][chs(256)] uint2 pack {h2(v_g,v_g+16), h2(v_g+8,v_g+24)}
    // with chs = ch ^ (((ch>>4)&3)<<2) so a lane's 4 consecutive ch are bank-spread.
    __shared__ __align__(16) uint16_t s_in[3 * 8 * 256 * 4];   // 48 KiB
    __shared__ __align__(16) uint2    buf2[4096];              // 32 KiB

    const int t  = threadIdx.x;
    const int l  = t & 63, w = t >> 6;
    const int c0 = l & 15, ql = l >> 4;
    const int b  = blockIdx.x >> 5;
    const int oh = blockIdx.x & 31;

    // ---- stage input rows oh-1..oh+1 (coalesced float4)
    #pragma unroll
    for (int i = 0; i < 24; ++i) {
        const int idx   = t + i * 256;
        const int part  = idx & 7;
        const int ch    = (idx >> 3) & 255;
        const int ihrel = idx >> 11;
        const int ih    = oh - 1 + ihrel;
        float4 ld = make_float4(0.f, 0.f, 0.f, 0.f);
        if ((unsigned)ih < 32u) {
            ld = *reinterpret_cast<const float4*>(
                in + ((((size_t)b * 256 + ch) * 32 + ih) * 32 + part * 4));
        }
        const int qq    = part >> 1;                 // iw>>3 group
        const int slotp = (qq == 0) ? 0 : (qq == 1) ? 2 : (qq == 2) ? 1 : 3;
        const int g0    = 4 * (part & 1);
        const int chs   = ch ^ (((ch >> 4) & 3) << 2);
        const int base  = (ihrel * 8 + g0) * 1024 + chs * 4 + slotp;
        s_in[base       ] = f2h16(ld.x);
        s_in[base + 1024] = f2h16(ld.y);
        s_in[base + 2048] = f2h16(ld.z);
        s_in[base + 3072] = f2h16(ld.w);
    }

    // ---- constant fragments. Convention everywhere: element i of a fragment
    // holds index k = 4*ql + i (matches verified D row layout).
    h4 Hp, Hn;
    #pragma unroll
    for (int i = 0; i < 4; ++i) {
        const int k = 4 * ql + i;
        const float s = (__popc(c0 & k) & 1) ? -1.f : 1.f;
        Hp[i] = (_Float16)s; Hn[i] = (_Float16)(-s);
    }
    h4 Bh[9];
    #pragma unroll
    for (int kk = 0; kk < 9; ++kk) {
        const float4 v = *reinterpret_cast<const float4*>(Bm + 256 * kk + 16 * c0 + 4 * ql);
        Bh[kk][0] = (_Float16)v.x; Bh[kk][1] = (_Float16)v.y;
        Bh[kk][2] = (_Float16)v.z; Bh[kk][3] = (_Float16)v.w;
    }
    h4 Gh[16];   // G[j'] for j' = 256a + 16*c0 + 4*ql + i
    #pragma unroll
    for (int a = 0; a < 16; ++a) {
        const float4 v = *reinterpret_cast<const float4*>(Gm + 256 * a + 16 * c0 + 4 * ql);
        Gh[a][0] = (_Float16)v.x; Gh[a][1] = (_Float16)v.y;
        Gh[a][2] = (_Float16)v.z; Gh[a][3] = (_Float16)v.w;
    }
    __syncthreads();

    const uint2* s2 = reinterpret_cast<const uint2*>(s_in);
    const int Lsw = l ^ ((l >> 2) & 3);
    const f4 zf = {0.f, 0.f, 0.f, 0.f};
    uint2 os[2][4], od[2][4];

    #pragma unroll
    for (int rq = 0; rq < 2; ++rq) {
        const int p = w + 4 * rq;     // quad: ow = p, p+8, p+16, p+24

        // ===== taps + pass0 b,c rounds:  st[a] = H * (X_a * H)
        h4 st[16][4];                 // [tile a][px]  (px: 0=p,1=p+8,2=p+16,3=p+24)
        #pragma unroll
        for (int kk = 0; kk < 9; ++kk) {
            const int kh = kk / 3, kw = kk % 3;
            const int iw = p - 1 + kw;
            const int g  = iw & 7;
            const int sb = (kh * 8 + g) * 256 + 16 * c0 + 4 * (ql ^ (c0 & 3));
            const uint4 r01 = *reinterpret_cast<const uint4*>(s2 + sb);
            const uint4 r23 = *reinterpret_cast<const uint4*>(s2 + sb + 2);
            uint32_t x0 = r01.x, y0 = r01.y, x1 = r01.z, y1 = r01.w;
            uint32_t x2 = r23.x, y2 = r23.y, x3 = r23.z, y3 = r23.w;
            if (kw == 0 && iw < 0) {          // p=0: x'=(0, y.lo), y'=x
                uint32_t tp;
                tp = x0; x0 = y0 << 16; y0 = tp;
                tp = x1; x1 = y1 << 16; y1 = tp;
                tp = x2; x2 = y2 << 16; y2 = tp;
                tp = x3; x3 = y3 << 16; y3 = tp;
            } else if (kw == 2 && iw > 7) {   // p=7: x'=y, y'=(x.hi, 0)
                uint32_t tp;
                tp = x0; x0 = y0; y0 = tp >> 16;
                tp = x1; x1 = y1; y1 = tp >> 16;
                tp = x2; x2 = y2; y2 = tp >> 16;
                tp = x3; x3 = y3; y3 = tp >> 16;
            }
            h4 fr[4];
            fr[0] = u2h4(lolo(x0, x1), lolo(x2, x3)) * Bh[kk];   // ow p
            fr[1] = u2h4(lolo(y0, y1), lolo(y2, y3)) * Bh[kk];   // ow p+8
            fr[2] = u2h4(hihi(x0, x1), hihi(x2, x3)) * Bh[kk];   // ow p+16
            fr[3] = u2h4(hihi(y0, y1), hihi(y2, y3)) * Bh[kk];   // ow p+24
            #pragma unroll
            for (int px = 0; px < 4; ++px) {
                const f4 d1 = mfma16(fr[px], Hp, zf);   // X*H   (jC round)
                const h4 h1 = cvt4(d1);
                const f4 d2 = mfma16(Hp, h1, zf);       // H*(..) (jB round)
                st[kk][px] = cvt4(d2);
            }
        }
        {
            const h4 z4 = {(_Float16)0.f, (_Float16)0.f, (_Float16)0.f, (_Float16)0.f};
            #pragma unroll
            for (int kk = 9; kk < 16; ++kk) {
                st[kk][0] = z4; st[kk][1] = z4; st[kk][2] = z4; st[kk][3] = z4;
            }
        }

        // ===== pass0 a-round: FWHT16 across tile index, in registers
        #pragma unroll
        for (int hh = 1; hh < 16; hh <<= 1) {
            #pragma unroll
            for (int gg = 0; gg < 16; gg += 2 * hh) {
                #pragma unroll
                for (int u = gg; u < gg + hh; ++u) {
                    #pragma unroll
                    for (int px = 0; px < 4; ++px) {
                        const h4 A = st[u][px], Bv = st[u + hh][px];
                        st[u][px]      = A + Bv;
                        st[u + hh][px] = A - Bv;
                    }
                }
            }
        }

        // ===== stage + permutation gather (buf2 time-shared: one wave per slot)
        uint2 garr[16][4];
        #pragma unroll
        for (int s = 0; s < 4; ++s) {
            if (w == s) {
                int4 Pv[16];
                #pragma unroll   // P prefetch half 1 (latency hides under stage)
                for (int a = 0; a < 8; ++a)
                    Pv[a] = *reinterpret_cast<const int4*>(P + 256 * a + 16 * c0 + 4 * ql);
                #pragma unroll   // stage: value j -> slot sigma(j), 2x b128 per tile
                for (int a = 0; a < 16; ++a) {
                    const uint2 UA = h4u(st[a][0]), UB = h4u(st[a][1]);
                    const uint2 UC = h4u(st[a][2]), UD = h4u(st[a][3]);
                    uint4* dst = reinterpret_cast<uint4*>(&buf2[256 * a + 4 * Lsw]);
                    dst[0] = make_uint4(lolo(UA.x, UC.x), lolo(UB.x, UD.x),
                                        hihi(UA.x, UC.x), hihi(UB.x, UD.x));
                    dst[1] = make_uint4(lolo(UA.y, UC.y), lolo(UB.y, UD.y),
                                        hihi(UA.y, UC.y), hihi(UB.y, UD.y));
                }
                #pragma unroll
                for (int a = 8; a < 16; ++a)
                    Pv[a] = *reinterpret_cast<const int4*>(P + 256 * a + 16 * c0 + 4 * ql);
                #pragma unroll   // gather: u-frag element (a,i) <- sigma(P[j'])
                for (int a = 0; a < 16; ++a) {
                    const int pj0 = Pv[a].x, pj1 = Pv[a].y, pj2 = Pv[a].z, pj3 = Pv[a].w;
                    garr[a][0] = buf2[sigma_slot(pj0)];
                    garr[a][1] = buf2[sigma_slot(pj1)];
                    garr[a][2] = buf2[sigma_slot(pj2)];
                    garr[a][3] = buf2[sigma_slot(pj3)];
                }
            }
            __syncthreads();   // hands buf2 to next wave (drains this wave's DS ops)
        }

        // ===== pass1: (u*G) -> jC',jB' rounds; a-round truncated via C-accum
        f4 sa[4] = {zf, zf, zf, zf}, da[4] = {zf, zf, zf, zf};
        #pragma unroll
        for (int a = 0; a < 16; ++a) {
            const uint32_t gx0 = garr[a][0].x, gy0 = garr[a][0].y;
            const uint32_t gx1 = garr[a][1].x, gy1 = garr[a][1].y;
            const uint32_t gx2 = garr[a][2].x, gy2 = garr[a][2].y;
            const uint32_t gx3 = garr[a][3].x, gy3 = garr[a][3].y;
            h4 fr[4];
            fr[0] = u2h4(lolo(gx0, gx1), lolo(gx2, gx3)) * Gh[a];
            fr[1] = u2h4(lolo(gy0, gy1), lolo(gy2, gy3)) * Gh[a];
            fr[2] = u2h4(hihi(gx0, gx1), hihi(gx2, gx3)) * Gh[a];
            fr[3] = u2h4(hihi(gy0, gy1), hihi(gy2, gy3)) * Gh[a];
            const h4 HA = (a & 1) ? Hn : Hp;
            #pragma unroll
            for (int px = 0; px < 4; ++px) {
                const f4 d1 = mfma16(fr[px], Hp, zf);   // U*H  (jC' round)
                const h4 h1 = cvt4(d1);
                sa[px] = mfma16(Hp, h1, sa[px]);        // +H*(..)  (oc row jA''=0)
                da[px] = mfma16(HA, h1, da[px]);        // +-H*(..) (oc row jA''=1)
            }
        }
        // pack per-quad outputs: .x = h2(ow p, p+16), .y = h2(ow p+8, p+24)
        #pragma unroll
        for (int i = 0; i < 4; ++i) {
            os[rq][i] = make_uint2(pkh2(sa[0][i], sa[2][i]), pkh2(sa[1][i], sa[3][i]));
            od[rq][i] = make_uint2(pkh2(da[0][i], da[2][i]), pkh2(da[1][i], da[3][i]));
        }
    }

    // ===== epilogue: stage h2 packs, cooperative coalesced f32 stores (R9 pattern)
    __syncthreads();
    #pragma unroll
    for (int rq = 0; rq < 2; ++rq) {
        const int g = w + 4 * rq;    // pack id == pixel-set base p
        #pragma unroll
        for (int i = 0; i < 4; ++i) {
            const int oc0 = 64 * ql + 16 * i + c0;
            buf2[oc0 * 8 + (g ^ ((oc0 >> 1) & 7))] = os[rq][i];
            const int oc1 = oc0 + 256;
            buf2[oc1 * 8 + (g ^ ((oc1 >> 1) & 7))] = od[rq][i];
        }
    }
    __syncthreads();
    #pragma unroll
    for (int it = 0; it < 16; ++it) {
        const int oc = it * 32 + (t >> 3), c = t & 7;
        const float S = Sm[oc], C = bias[oc];
        float o[4];
        #pragma unroll
        for (int e = 0; e < 4; ++e) {
            const int ow = 4 * c + e, gg = ow & 7, sh = ow >> 3;
            const uint2 u = buf2[oc * 8 + (gg ^ ((oc >> 1) & 7))];
            const uint32_t word = (sh & 1) ? u.y : u.x;
            const uint16_t hb = (sh >> 1) ? (uint16_t)(word >> 16)
                                          : (uint16_t)(word & 0xffffu);
            o[e] = S * h16f(hb) + C;
        }
        *reinterpret_cast<float4*>(
            out + ((size_t)b * 512 + oc) * 1024 + (size_t)oh * 32 + 4 * c)
            = make_float4(o[0], o[1], o[2], o[3]);
    }
}

extern "C" void kernel_launch(void* const* d_in, const int* in_sizes, int n_in,
                              void* d_out, int out_size, void* d_ws, size_t ws_size,
                              hipStream_t stream) {
    const float* in   = (const float*)d_in[0];
    const float* Bm   = (const float*)d_in[1];
    const float* Gm   = (const float*)d_in[2];
    const float* Sm   = (const float*)d_in[3];
    const float* bias = (const float*)d_in[4];
    const int*   P    = (const int*)d_in[5];
    float* out = (float*)d_out;
    (void)d_ws; (void)ws_size;

    dim3 grid(16 * 32), block(256);
    fastfood_kernel<<<grid, block, 0, stream>>>(in, Bm, Gm, Sm, bias, P, out);
}

// Round 9
// 124.979 us; speedup vs baseline: 1.4796x; 1.4796x over previous
//
#include <hip/hip_runtime.h>
#include <hip/hip_bf16.h>
#include <stdint.h>

// Fastfood 2D conv, MI355X. fp32 I/O:
// input (16,256,32,32), B/G/S (1,4096), bias (512), P (4096) i32 -> out (16,512,32,32).
// Per pixel: patch j=kk*256+ch (2304, pad 4096), *B, FWHT4096, perm P, *G, FWHT4096,
// *S[0:512]+bias.
//
// R4: pixel QUADS (ow = p, p+8, p+16, p+24), 4 px per uint2 LDS slot (b64 exchanges).
// R5: fp16-native pipeline (h2 regs, v_pk_add_f16 butterflies, bitcast exchanges).
// R6: WAR-barrier elimination (own-partition write-backs).
// R7: truncated second FWHT; thread t owns oc=t (sum) and oc=256+t (alt-sum).
// R8: b64 tap reads; intra-wave B<->C exchanges without barriers; single kernel.
// R9: register accumulation of outputs + one coalesced block-end epilogue
//     (fixed R8's L2 RMW write amplification).
// R10 (REVERTED): wave-level MFMA reformulation spilled (~400 VGPR live) ->
//     scratch traffic 88/152 MB. Thread-level mapping keeps 32 VGPR live/thread.
// R11: (a) TAP HOISTING: the 8 quads' 72 tap reads cover only 24 distinct
//     (kh,g) uint2 slots -> read once into registers (+48 VGPR; occupancy is
//     LDS-bound so free). s_in is then DEAD after the hoist.
//     (b) DOUBLE-BUFFERED EXCHANGE: reuse dead s_in's first 32KB as bufB for
//     pass-1 exchanges. The perm-gather reads bufA while C'-writes go to bufB
//     -> the WAR barrier after the gather is ELIMINATED. 3 barriers/quad
//     (all RAW, provably required): A-exchange, gather, final A-read.
// LDS: s_in 48KB + bufA 32KB = 80KB -> 2 blocks/CU.

typedef _Float16 h2 __attribute__((ext_vector_type(2)));

__device__ __forceinline__ uint16_t f2h16(float f) {
    union { _Float16 h; uint16_t u; } c; c.h = (_Float16)f; return c.u;
}
__device__ __forceinline__ float h16f(uint16_t u) {
    union { _Float16 h; uint16_t u; } c; c.u = u; return (float)c.h;
}
__device__ __forceinline__ int swz(int j) {
    return j ^ ((j >> 5) & 7) ^ (((j >> 8) & 1) * 24) ^ (((j >> 9) & 1) * 8);
}
__device__ __forceinline__ uint32_t h2u(h2 v) {
    union { h2 h; uint32_t u; } c; c.h = v; return c.u;
}
__device__ __forceinline__ h2 u2h(uint32_t x) {
    union { h2 h; uint32_t u; } c; c.u = x; return c.h;
}
__device__ __forceinline__ h2 pkh(float a, float b) {
    h2 r; r.x = (_Float16)a; r.y = (_Float16)b; return r;
}
__device__ __forceinline__ void h16h(h2* x) {
    #pragma unroll
    for (int h = 1; h < 16; h <<= 1) {
        #pragma unroll
        for (int g = 0; g < 16; g += 2 * h) {
            #pragma unroll
            for (int u = g; u < g + h; ++u) {
                h2 a = x[u], b = x[u + h];
                x[u]     = a + b;   // -> v_pk_add_f16
                x[u + h] = a - b;
            }
        }
    }
}
// truncated stride-256 round: s = sum_r x[r], d = sum_r (-1)^r x[r]
__device__ __forceinline__ void trunc16(const h2* x, h2& s, h2& d) {
    h2 sp[8], sm[8];
    #pragma unroll
    for (int i = 0; i < 8; ++i) {
        sp[i] = x[2 * i] + x[2 * i + 1];
        sm[i] = x[2 * i] - x[2 * i + 1];
    }
    #pragma unroll
    for (int h = 4; h >= 1; h >>= 1) {
        #pragma unroll
        for (int i = 0; i < h; ++i) { sp[i] = sp[i] + sp[i + h]; sm[i] = sm[i] + sm[i + h]; }
    }
    s = sp[0]; d = sm[0];
}
// slot k of a quad's packed output pair {s0,s1}: k=0->s0.x(ow p), 1->s1.x(p+8),
// 2->s0.y(p+16), 3->s1.y(p+24). k is compile-time under unroll.
__device__ __forceinline__ _Float16 slotk(const uint2& u, int k) {
    const h2 a = u2h(u.x), c = u2h(u.y);
    return (k == 0) ? a.x : (k == 1) ? c.x : (k == 2) ? a.y : c.y;
}

__global__ __launch_bounds__(256, 2)
void fastfood_kernel(const float* __restrict__ in,
                     const float* __restrict__ Bm,
                     const float* __restrict__ Gm,
                     const float* __restrict__ Sm,
                     const float* __restrict__ bias,
                     const int* __restrict__ P,
                     float* __restrict__ out)
{
    // s_in: [kh(3)][iwm(8)][ch(256)] of uint2 = {(v_iwm, v_iwm+16),(v_iwm+8, v_iwm+24)} f16.
    // After tap hoisting, its first 32KB is reused as bufB (pass-1 exchange buffer).
    __shared__ __align__(16) uint16_t s_in[3 * 8 * 256 * 4];   // 48 KiB
    __shared__ __align__(16) uint2    bufA[4096];              // 32 KiB

    const int t  = threadIdx.x;
    const int t1 = t >> 4, t0 = t & 15;
    const int b  = blockIdx.x >> 5;
    const int oh = blockIdx.x & 31;

    // ---- stage input rows oh-1..oh+1 into LDS (coalesced float4 reads)
    #pragma unroll
    for (int i = 0; i < 24; ++i) {
        const int idx   = t + i * 256;
        const int part  = idx & 7;
        const int ch    = (idx >> 3) & 255;
        const int ihrel = idx >> 11;
        const int ih    = oh - 1 + ihrel;
        float4 ld = make_float4(0.f, 0.f, 0.f, 0.f);
        if ((unsigned)ih < 32u) {
            ld = *reinterpret_cast<const float4*>(
                in + ((((size_t)b * 256 + ch) * 32 + ih) * 32 + part * 4));
        }
        const int q    = part >> 1;                  // iw>>3 for this float4
        const int slot = (q == 0) ? 0 : (q == 1) ? 2 : (q == 2) ? 1 : 3;
        const int g0   = 4 * (part & 1);             // iwm of ld.x
        const int base = (ihrel * 8 + g0) * 1024 + ch * 4 + slot;
        s_in[base       ] = f2h16(ld.x);
        s_in[base + 1024] = f2h16(ld.y);
        s_in[base + 2048] = f2h16(ld.z);
        s_in[base + 3072] = f2h16(ld.w);
    }

    // ---- constants
    float Bf[9];
    #pragma unroll
    for (int r = 0; r < 9; ++r) Bf[r] = Bm[r * 256 + t];
    h2 Bh[9];
    #pragma unroll
    for (int r = 0; r < 9; ++r) Bh[r] = pkh(Bf[r], Bf[r]);

    h2 Gh[16]; int PAv[16];
    #pragma unroll
    for (int q = 0; q < 4; ++q) {
        const int4   pv = *reinterpret_cast<const int4*>(P + 16 * t + 4 * q);
        const float4 gv = *reinterpret_cast<const float4*>(Gm + 16 * t + 4 * q);
        PAv[4 * q + 0] = swz(pv.x); PAv[4 * q + 1] = swz(pv.y);
        PAv[4 * q + 2] = swz(pv.z); PAv[4 * q + 3] = swz(pv.w);
        Gh[4 * q + 0] = pkh(gv.x, gv.x); Gh[4 * q + 1] = pkh(gv.y, gv.y);
        Gh[4 * q + 2] = pkh(gv.z, gv.z); Gh[4 * q + 3] = pkh(gv.w, gv.w);
    }
    __syncthreads();                               // s_in staged

    // ---- TAP HOIST: all 24 distinct (kh,g) taps for this thread -> registers.
    // s_in is dead afterwards; its first 32KB becomes bufB.
    const uint2* s2 = reinterpret_cast<const uint2*>(s_in);
    uint2 tap[3][8];
    #pragma unroll
    for (int kh = 0; kh < 3; ++kh)
        #pragma unroll
        for (int g = 0; g < 8; ++g)
            tap[kh][g] = s2[(kh * 8 + g) * 256 + t];   // bank 2t%32: 2-way, free
    uint2* bufB = reinterpret_cast<uint2*>(s_in);

    uint2 os[8], od[8];                       // per-quad packed outputs (registers)

    #pragma unroll
    for (int p = 0; p < 8; ++p) {             // pixel quad (ow = p, p+8, p+16, p+24)
        h2 x0[16], x1[16];                    // x0=(p, p+16), x1=(p+8, p+24)
        #pragma unroll
        for (int r = 0; r < 9; ++r) {
            const int kh = r / 3, kw = r % 3;
            const int iw = p - 1 + kw;        // in [-1, 8]; compile-time per body
            const uint2 u = tap[kh][iw & 7];
            h2 a = u2h(u.x), c = u2h(u.y);    // a=(v_g, v_g+16), c=(v_g+8, v_g+24)
            h2 ta = a, tc = c;
            if (iw < 0) {                     // p=0,kw=0: x0=(0,v15), x1=(v7,v23)
                ta.x = (_Float16)0.f; ta.y = c.x;
                tc = a;
            } else if (iw > 7) {              // p=7,kw=2: x0=(v8,v24), x1=(v16,0)
                ta = c;
                tc.x = a.y; tc.y = (_Float16)0.f;
            }
            x0[r] = Bh[r] * ta;               // -> v_pk_mul_f16
            x1[r] = Bh[r] * tc;
        }
        #pragma unroll
        for (int r = 9; r < 16; ++r) {
            x0[r] = pkh(0.f, 0.f);
            x1[r] = pkh(0.f, 0.f);
        }

        // ===== pass 0 (bufA): A(str256) -> B(str16) -> C(str1), stage for gather
        h16h(x0); h16h(x1);                   // round A
        #pragma unroll                        // own slots; prev bufA reads (quad p-1
        for (int r = 0; r < 16; ++r)          // gathers) fenced by its S3 barrier
            bufA[swz(256 * r + t)] = make_uint2(h2u(x0[r]), h2u(x1[r]));
        __syncthreads();                      // S1: RAW, cross-wave (A -> B)
        #pragma unroll
        for (int r = 0; r < 16; ++r) {
            const uint2 u = bufA[swz(256 * t1 + 16 * r + t0)];
            x0[r] = u2h(u.x); x1[r] = u2h(u.y);
        }
        h16h(x0); h16h(x1);                   // round B
        #pragma unroll                        // own slots
        for (int r = 0; r < 16; ++r)
            bufA[swz(256 * t1 + 16 * r + t0)] = make_uint2(h2u(x0[r]), h2u(x1[r]));
        // NO barrier: B->C exchange stays within group t1 = 16 contiguous threads
        // (same wave); lgkmcnt ordering suffices.
        #pragma unroll
        for (int r = 0; r < 16; ++r) {
            const uint2 u = bufA[swz(256 * t1 + 16 * t0 + r)];
            x0[r] = u2h(u.x); x1[r] = u2h(u.y);
        }
        h16h(x0); h16h(x1);                   // round C
        #pragma unroll                        // own slots (stage for gather)
        for (int r = 0; r < 16; ++r)
            bufA[swz(256 * t1 + 16 * t0 + r)] = make_uint2(h2u(x0[r]), h2u(x1[r]));
        __syncthreads();                      // S2: RAW, cross-wave (before gather)

        // ===== permutation + G: gather from bufA INTO C-layout (thread t: j=16t+r)
        #pragma unroll
        for (int r = 0; r < 16; ++r) {
            const uint2 u = bufA[PAv[r]];
            x0[r] = Gh[r] * u2h(u.x);
            x1[r] = Gh[r] * u2h(u.y);
        }

        // ===== pass 1 (bufB): C(str1) -> B(str16) -> A(str256, truncated).
        // Writing bufB while gathers read bufA -> NO WAR barrier needed here.
        h16h(x0); h16h(x1);                   // round C'
        #pragma unroll
        for (int r = 0; r < 16; ++r)
            bufB[swz(256 * t1 + 16 * t0 + r)] = make_uint2(h2u(x0[r]), h2u(x1[r]));
        // NO barrier: C->B intra-wave (group t1).
        #pragma unroll
        for (int r = 0; r < 16; ++r) {
            const uint2 u = bufB[swz(256 * t1 + 16 * r + t0)];
            x0[r] = u2h(u.x); x1[r] = u2h(u.y);
        }
        h16h(x0); h16h(x1);                   // round B'
        #pragma unroll                        // own slots
        for (int r = 0; r < 16; ++r)
            bufB[swz(256 * t1 + 16 * r + t0)] = make_uint2(h2u(x0[r]), h2u(x1[r]));
        __syncthreads();                      // S3: RAW, cross-wave (B' -> A read)
        #pragma unroll
        for (int r = 0; r < 16; ++r) {        // A-layout: x[r] = j = 256r + t
            const uint2 u = bufB[swz(256 * r + t)];
            x0[r] = u2h(u.x); x1[r] = u2h(u.y);
        }
        // truncated round A: oc = t (sum), oc = 256+t (alternating sum)
        h2 s0, d0, s1, d1;
        trunc16(x0, s0, d0);                  // (ow p, p+16)
        trunc16(x1, s1, d1);                  // (ow p+8, p+24)
        os[p] = make_uint2(h2u(s0), h2u(s1)); // static index (unrolled) -> registers
        od[p] = make_uint2(h2u(d0), h2u(d1));
        // next quad's A-write (bufA) is safe: its last readers (gathers) are
        // fenced by S3 above.
    }

    // ===== block-end epilogue =====
    // Repack to ow-major: U[i]/V[i] = uint2 covering cols 4i..4i+3 of rows oc=t / 256+t.
    // col w: quad p = w&7, slot k = w>>3. U[i]: k = i>>1, quads p0..p0+3, p0 = (i&1)*4.
    uint2 U[8], V[8];
    #pragma unroll
    for (int i = 0; i < 8; ++i) {
        const int k = i >> 1, p0 = (i & 1) * 4;
        h2 lo, hi;
        lo.x = slotk(os[p0], k);     lo.y = slotk(os[p0 + 1], k);
        hi.x = slotk(os[p0 + 2], k); hi.y = slotk(os[p0 + 3], k);
        U[i] = make_uint2(h2u(lo), h2u(hi));
        lo.x = slotk(od[p0], k);     lo.y = slotk(od[p0 + 1], k);
        hi.x = slotk(od[p0 + 2], k); hi.y = slotk(od[p0 + 3], k);
        V[i] = make_uint2(h2u(lo), h2u(hi));
    }

    __syncthreads();                          // WAR: quad-7 bufA gathers done everywhere
    // Stage rows into bufA: [oc*8 + (i ^ ((oc>>1)&7))]. For oc=t and oc=256+t the
    // swizzle term is identical ((t>>1)&7). 4-cycle-optimal b64 banking.
    {
        const int sw = (t >> 1) & 7;
        #pragma unroll
        for (int i = 0; i < 8; ++i) {
            bufA[(size_t)t * 8 + (i ^ sw)]         = U[i];
            bufA[(size_t)(256 + t) * 8 + (i ^ sw)] = V[i];
        }
    }
    __syncthreads();                          // RAW
    // Cooperative store: 16 iters; per wave-instr 8 rows x full 128B lines.
    #pragma unroll
    for (int it = 0; it < 16; ++it) {
        const int oc = it * 32 + (t >> 3);
        const int c  = t & 7;
        const uint2 u = bufA[(size_t)oc * 8 + (c ^ ((oc >> 1) & 7))];
        const h2 lo = u2h(u.x), hi = u2h(u.y);
        const float S = Sm[oc], C = bias[oc];
        const float4 v = make_float4(S * (float)lo.x + C, S * (float)lo.y + C,
                                     S * (float)hi.x + C, S * (float)hi.y + C);
        *reinterpret_cast<float4*>(
            out + ((size_t)b * 512 + oc) * 1024 + (size_t)oh * 32 + 4 * c) = v;
    }
}

extern "C" void kernel_launch(void* const* d_in, const int* in_sizes, int n_in,
                              void* d_out, int out_size, void* d_ws, size_t ws_size,
                              hipStream_t stream) {
    const float* in   = (const float*)d_in[0];
    const float* Bm   = (const float*)d_in[1];
    const float* Gm   = (const float*)d_in[2];
    const float* Sm   = (const float*)d_in[3];
    const float* bias = (const float*)d_in[4];
    const int*   P    = (const int*)d_in[5];
    float* out = (float*)d_out;
    (void)d_ws; (void)ws_size;

    dim3 grid(16 * 32), block(256);
    fastfood_kernel<<<grid, block, 0, stream>>>(in, Bm, Gm, Sm, bias, P, out);
}